// Round 6
// baseline (25.275 us; speedup 1.0000x reference)
//
#include <hip/hip_runtime.h>

// diff_round(x) = x - sin(2*pi*x)/(2*pi).
// v_sin_f32 input is in REVOLUTIONS: __builtin_amdgcn_sinf(x) == sin(2*pi*x).
#define INV_TWO_PI_F 0.15915494309189533577f

__device__ __forceinline__ float dround(float x) {
    return __builtin_fmaf(__builtin_amdgcn_sinf(x), -INV_TWO_PI_F, x);
}

struct AreaData {
    float4 im, ed, m0, m1, m2, m3, md;
};

// lane t owns 4 consecutive pixels: pixel q = 4*t + k -> row i = t>>2, col c = 4*(t&3)+k
__device__ __forceinline__ AreaData load_area(
    const float* __restrict__ img, const float* __restrict__ mask,
    const float* __restrict__ mid, const float* __restrict__ edge,
    size_t p, int t)
{
    AreaData a;
    a.im = reinterpret_cast<const float4*>(img )[p * 64 + t];
    a.ed = reinterpret_cast<const float4*>(edge)[p * 64 + t];
    const float4* mk = reinterpret_cast<const float4*>(mask) + p * 256 + 4 * t;
    a.m0 = mk[0]; a.m1 = mk[1]; a.m2 = mk[2]; a.m3 = mk[3];
    a.md = reinterpret_cast<const float4*>(mid)[p];
    return a;
}

// mid is exactly {0,1} (jnp.round of uniform); hdround fixes {0,1}, and
// dround(1-x) == 1-dround(x), so differentiable_eq(m, mid) collapses to
// select(mid, d5(m), 1-d5(m)) at the point feeding differentiable_and.
__device__ __forceinline__ void process_area(
    const AreaData& A, const size_t p, const int t,
    float* __restrict__ out_edges, float* __restrict__ out_scalar)
{
    const bool h0 = A.md.x > 0.5f;
    const bool h1 = A.md.y > 0.5f;
    const bool h2 = A.md.z > 0.5f;
    const bool h3 = A.md.w > 0.5f;

    const float imv[4] = {A.im.x, A.im.y, A.im.z, A.im.w};
    const float edv[4] = {A.ed.x, A.ed.y, A.ed.z, A.ed.w};
    const float4 mm[4] = {A.m0, A.m1, A.m2, A.m3};

    float mc[4], mi[4];
    #pragma unroll
    for (int k = 0; k < 4; ++k) {
        float w0 = mm[k].x, w1 = mm[k].y, w2 = mm[k].z, w3 = mm[k].w;
        #pragma unroll
        for (int r = 0; r < 5; ++r) {
            w0 = dround(w0); w1 = dround(w1); w2 = dround(w2); w3 = dround(w3);
        }
        const float da0 = h0 ? w0 : 1.0f - w0;
        const float da1 = h1 ? w1 : 1.0f - w1;
        const float da2 = h2 ? w2 : 1.0f - w2;
        const float da3 = h3 ? w3 : 1.0f - w3;
        mc[k] = dround(da0 * da1) * dround(da2 * da3);
        mi[k] = mc[k] * imv[k];
    }

    // reduction 1 (butterfly -> all lanes): sum(mc), sum(mc*img)
    float s1 = mc[0] + mc[1] + mc[2] + mc[3];
    float s2 = mi[0] + mi[1] + mi[2] + mi[3];
    #pragma unroll
    for (int m = 1; m < 64; m <<= 1) {
        s1 += __shfl_xor(s1, m);
        s2 += __shfl_xor(s2, m);
    }
    const float inv_d = __builtin_amdgcn_rcpf(s1 + 1e-8f);
    const float meann = s2 * inv_d;

    // neighbors (zero-padded shifts): rows from lanes t+-4, cols within lane/lane t+-1
    float pr[4], nr[4];
    #pragma unroll
    for (int k = 0; k < 4; ++k) {
        const float u = __shfl_up(mc[k], 4);
        const float d = __shfl_down(mc[k], 4);
        pr[k] = (t >= 4)  ? u : 0.0f;
        nr[k] = (t < 60) ? d : 0.0f;
    }
    const float lEdge = __shfl_up(mc[3], 1);
    const float rEdge = __shfl_down(mc[0], 1);
    float lf[4], rt[4];
    lf[0] = ((t & 3) > 0) ? lEdge : 0.0f;
    lf[1] = mc[0]; lf[2] = mc[1]; lf[3] = mc[2];
    rt[3] = ((t & 3) < 3) ? rEdge : 0.0f;
    rt[0] = mc[1]; rt[1] = mc[2]; rt[2] = mc[3];

    // erosion + masked edges + reduction-2 partials
    float me[4];
    float r1 = 0.0f, r2 = 0.0f;
    #pragma unroll
    for (int k = 0; k < 4; ++k) {
        const float ed_fb = 1.0f - (nr[k] * pr[k] + (1.0f - nr[k]) * (1.0f - pr[k]));
        const float ed_ud = 1.0f - (rt[k] * lf[k] + (1.0f - rt[k]) * (1.0f - lf[k]));
        const float s0a = ed_fb * mc[k];
        const float s0b = ed_ud * mc[k];
        const float sb0 = s0a * s0b + (1.0f - s0a) * s0a + (1.0f - s0b) * s0a;
        me[k] = (1.0f - sb0) * mc[k] * edv[k];
        const float vv = (mi[k] - meann) * mc[k];
        r1 += vv * vv;
        r2 += me[k];
    }

    float4 o;
    o.x = me[0]; o.y = me[1]; o.z = me[2]; o.w = me[3];
    reinterpret_cast<float4*>(out_edges)[p * 64 + t] = o;

    // reduction 2 (butterfly): sum(var-terms), sum(masked_edges)
    #pragma unroll
    for (int m = 1; m < 64; m <<= 1) {
        r1 += __shfl_xor(r1, m);
        r2 += __shfl_xor(r2, m);
    }
    if (t == 0) {
        const float varr = r1 * inv_d;
        const float loss = r2 * (1.0f / 256.0f);
        out_scalar[p] = varr * loss * 1000.0f;
    }
}

// Persistent software-pipelined waves: 4096 waves, each owns 4 areas strided
// by NW (machine sweeps contiguous chunks per generation). Double-buffered:
// next area's loads are in flight while the current one computes, so memory
// demand is continuous instead of 2 bursty generations.
__global__ void __launch_bounds__(256, 4)
deconv_area_kernel(const float* __restrict__ img,
                   const float* __restrict__ mask,
                   const float* __restrict__ mid,
                   const float* __restrict__ edge,
                   float* __restrict__ out_edges,
                   float* __restrict__ out_scalar,
                   int n_waves)
{
    const int w = blockIdx.x * 4 + (threadIdx.x >> 6);   // global wave id
    const int t = threadIdx.x & 63;
    const size_t NW = (size_t)n_waves;

    const size_t p0 = (size_t)w;
    const size_t p1 = p0 + NW;
    const size_t p2 = p1 + NW;
    const size_t p3 = p2 + NW;

    AreaData A = load_area(img, mask, mid, edge, p0, t);
    AreaData B = load_area(img, mask, mid, edge, p1, t);
    process_area(A, p0, t, out_edges, out_scalar);
    A = load_area(img, mask, mid, edge, p2, t);
    process_area(B, p1, t, out_edges, out_scalar);
    B = load_area(img, mask, mid, edge, p3, t);
    process_area(A, p2, t, out_edges, out_scalar);
    process_area(B, p3, t, out_edges, out_scalar);
}

extern "C" void kernel_launch(void* const* d_in, const int* in_sizes, int n_in,
                              void* d_out, int out_size, void* d_ws, size_t ws_size,
                              hipStream_t stream)
{
    const float* img  = (const float*)d_in[0];  // [B,A,16,16,1]
    const float* mask = (const float*)d_in[1];  // [B,A,16,16,4]
    const float* mid  = (const float*)d_in[2];  // [B,A,4]
    const float* edge = (const float*)d_in[3];  // [B,A,16,16]

    const int n_areas = in_sizes[3] / 256;      // B*A (16384)
    const int n_waves = n_areas / 4;            // 4096
    const int n_blocks = n_waves / 4;           // 1024

    float* out0 = (float*)d_out;                         // [B,A,16,16,1]
    float* out1 = (float*)d_out + (size_t)n_areas * 256; // [B,A]

    deconv_area_kernel<<<dim3(n_blocks), dim3(256), 0, stream>>>(
        img, mask, mid, edge, out0, out1, n_waves);
}

// Round 7
// 24.277 us; speedup vs baseline: 1.0411x; 1.0411x over previous
//
#include <hip/hip_runtime.h>

// diff_round(x) = x - sin(2*pi*x)/(2*pi).
// v_sin_f32 input is in REVOLUTIONS: __builtin_amdgcn_sinf(x) == sin(2*pi*x).
#define INV_TWO_PI_F 0.15915494309189533577f

__device__ __forceinline__ float dround(float x) {
    return __builtin_fmaf(__builtin_amdgcn_sinf(x), -INV_TWO_PI_F, x);
}

// One 64-lane wave per area; lane t owns 4 consecutive pixels:
// pixel q = 4*t + k  ->  row i = t>>2, col c = 4*(t&3) + k.
// mid is exactly {0,1} (jnp.round of uniform); hdround fixes {0,1}, and
// dround(1-x) == 1-dround(x), so differentiable_eq(m, mid) reduces to
// select(mid, d5(m), 1-d5(m)) at the point feeding differentiable_and.
__global__ void __launch_bounds__(256, 8)
deconv_area_kernel(const float* __restrict__ img,
                   const float* __restrict__ mask,
                   const float* __restrict__ mid,
                   const float* __restrict__ edge,
                   float* __restrict__ out_edges,
                   float* __restrict__ out_scalar)
{
    const int wid = blockIdx.x * 4 + (threadIdx.x >> 6);  // area index
    const int t   = threadIdx.x & 63;
    const size_t p = (size_t)wid;

    // ---- issue all loads up front ----
    const float4 im4 = reinterpret_cast<const float4*>(img )[p * 64 + t];
    const float4 ed4 = reinterpret_cast<const float4*>(edge)[p * 64 + t];
    const float4* mk = reinterpret_cast<const float4*>(mask) + p * 256 + 4 * t;
    const float4 mm0 = mk[0], mm1 = mk[1], mm2 = mk[2], mm3 = mk[3];
    const float4 md  = reinterpret_cast<const float4*>(mid)[p];   // broadcast

    const bool h0 = md.x > 0.5f;
    const bool h1 = md.y > 0.5f;
    const bool h2 = md.z > 0.5f;
    const bool h3 = md.w > 0.5f;

    const float imv[4] = {im4.x, im4.y, im4.z, im4.w};
    const float edv[4] = {ed4.x, ed4.y, ed4.z, ed4.w};
    const float4 mm[4] = {mm0, mm1, mm2, mm3};

    // ---- filter_mask_of_intrest per pixel ----
    float mc[4], mi[4];
    #pragma unroll
    for (int k = 0; k < 4; ++k) {
        // 5-deep dround chain per channel, then select by mid-bit
        float w0 = mm[k].x, w1 = mm[k].y, w2 = mm[k].z, w3 = mm[k].w;
        #pragma unroll
        for (int r = 0; r < 5; ++r) {
            w0 = dround(w0); w1 = dround(w1); w2 = dround(w2); w3 = dround(w3);
        }
        const float da0 = h0 ? w0 : 1.0f - w0;
        const float da1 = h1 ? w1 : 1.0f - w1;
        const float da2 = h2 ? w2 : 1.0f - w2;
        const float da3 = h3 ? w3 : 1.0f - w3;
        mc[k] = dround(da0 * da1) * dround(da2 * da3);
        mi[k] = mc[k] * imv[k];
    }

    // ---- reduction 1 (butterfly -> all lanes): sum(mc), sum(mc*img) ----
    float s1 = mc[0] + mc[1] + mc[2] + mc[3];
    float s2 = mi[0] + mi[1] + mi[2] + mi[3];
    #pragma unroll
    for (int m = 1; m < 64; m <<= 1) {
        s1 += __shfl_xor(s1, m);
        s2 += __shfl_xor(s2, m);
    }
    const float inv_d = __builtin_amdgcn_rcpf(s1 + 1e-8f);
    const float meann = s2 * inv_d;

    // ---- neighbors (zero-padded shifts) ----
    float pr[4], nr[4];                       // row i-1 / i+1 from lanes t-4 / t+4
    #pragma unroll
    for (int k = 0; k < 4; ++k) {
        const float u = __shfl_up(mc[k], 4);
        const float d = __shfl_down(mc[k], 4);
        pr[k] = (t >= 4)  ? u : 0.0f;
        nr[k] = (t < 60) ? d : 0.0f;
    }
    const float lEdge = __shfl_up(mc[3], 1);
    const float rEdge = __shfl_down(mc[0], 1);
    float lf[4], rt[4];                       // col c-1 / c+1
    lf[0] = ((t & 3) > 0) ? lEdge : 0.0f;
    lf[1] = mc[0]; lf[2] = mc[1]; lf[3] = mc[2];
    rt[3] = ((t & 3) < 3) ? rEdge : 0.0f;
    rt[0] = mc[1]; rt[1] = mc[2]; rt[2] = mc[3];

    // ---- erosion + masked edges + reduction-2 partials ----
    float me[4];
    float r1 = 0.0f, r2 = 0.0f;
    #pragma unroll
    for (int k = 0; k < 4; ++k) {
        const float ed_fb = 1.0f - (nr[k] * pr[k] + (1.0f - nr[k]) * (1.0f - pr[k]));
        const float ed_ud = 1.0f - (rt[k] * lf[k] + (1.0f - rt[k]) * (1.0f - lf[k]));
        const float s0a = ed_fb * mc[k];
        const float s0b = ed_ud * mc[k];
        const float sb0 = s0a * s0b + (1.0f - s0a) * s0a + (1.0f - s0b) * s0a;
        me[k] = (1.0f - sb0) * mc[k] * edv[k];
        const float vv = (mi[k] - meann) * mc[k];
        r1 += vv * vv;
        r2 += me[k];
    }

    float4 o;
    o.x = me[0]; o.y = me[1]; o.z = me[2]; o.w = me[3];
    reinterpret_cast<float4*>(out_edges)[p * 64 + t] = o;

    // ---- reduction 2 (butterfly): sum(var-terms), sum(masked_edges) ----
    #pragma unroll
    for (int m = 1; m < 64; m <<= 1) {
        r1 += __shfl_xor(r1, m);
        r2 += __shfl_xor(r2, m);
    }
    if (t == 0) {
        const float varr = r1 * inv_d;
        const float loss = r2 * (1.0f / 256.0f);
        out_scalar[p] = varr * loss * 1000.0f;
    }
}

extern "C" void kernel_launch(void* const* d_in, const int* in_sizes, int n_in,
                              void* d_out, int out_size, void* d_ws, size_t ws_size,
                              hipStream_t stream)
{
    const float* img  = (const float*)d_in[0];  // [B,A,16,16,1]
    const float* mask = (const float*)d_in[1];  // [B,A,16,16,4]
    const float* mid  = (const float*)d_in[2];  // [B,A,4]
    const float* edge = (const float*)d_in[3];  // [B,A,16,16]

    const int n_areas = in_sizes[3] / 256;      // B*A (16384)

    float* out0 = (float*)d_out;                         // [B,A,16,16,1]
    float* out1 = (float*)d_out + (size_t)n_areas * 256; // [B,A]

    deconv_area_kernel<<<dim3(n_areas / 4), dim3(256), 0, stream>>>(
        img, mask, mid, edge, out0, out1);
}